// Round 1
// baseline (1961.087 us; speedup 1.0000x reference)
//
#include <hip/hip_runtime.h>

// Problem constants (fixed-shape problem)
#define NV 20000
#define NE 240000
#define DD 512
#define PER 5000
#define DEG 16
#define EPB 80000            // edges per level block
#define SCALE 0.07216878364870323f   // (3*64)^-0.5
#define MAXDEG 96

// ---------------------------------------------------------------------------
// init: copy node_feats into both output halves (td at 0, bu at NV*DD)
__global__ void init_copy(const float* __restrict__ nf, float* __restrict__ out) {
    int i = blockIdx.x * 256 + threadIdx.x;              // exactly NV*DD/4 threads
    float4 v = reinterpret_cast<const float4*>(nf)[i];
    reinterpret_cast<float4*>(out)[i] = v;
    reinterpret_cast<float4*>(out + (size_t)NV * DD)[i] = v;
}

// ---------------------------------------------------------------------------
// fold: build 3 [512][16] matrices:
//  arr0 = wnJI_bu (cols 0-7 aw_j fold, 8-15 aw_i fold of Wn_bu)
//  arr1 = wnJI_td
//  arr2 = weA (cols 0-7 bu edge-alpha fold, 8-15 td)
__global__ void fold_kernel(
    const float* __restrict__ Wn_bu, const float* __restrict__ attn_bu,
    const float* __restrict__ Wn_td, const float* __restrict__ attn_td,
    const float* __restrict__ We_bu, const float* __restrict__ We_td,
    float* __restrict__ fold)
{
    int idx = blockIdx.x * 256 + threadIdx.x;
    if (idx >= 3 * 8192) return;
    int arr = idx >> 13;
    int r = idx & 8191;
    int d = r >> 4;
    int o = r & 15;
    int h = o & 7;
    const float* W; const float* attn; int awOff;
    if (arr == 0)      { W = Wn_bu; attn = attn_bu; awOff = (o < 8) ? 0 : 64; }
    else if (arr == 1) { W = Wn_td; attn = attn_td; awOff = (o < 8) ? 0 : 64; }
    else               { W = (o < 8) ? We_bu : We_td; attn = (o < 8) ? attn_bu : attn_td; awOff = 128; }
    float s = 0.f;
    for (int cc = 0; cc < 64; ++cc)
        s += W[d * 512 + h * 64 + cc] * attn[h * 192 + awOff + cc];
    fold[idx] = s;
}

// ---------------------------------------------------------------------------
// rowdot16: out[r][0..16) = rows[r][0..512) dot W[:,o]   (W is [512][16])
// one wave per row, weights staged transposed in LDS
__global__ __launch_bounds__(256) void rowdot16(
    const float* __restrict__ rows, int nRows,
    const float* __restrict__ W, float* __restrict__ out)
{
    __shared__ __align__(16) float Wt[16][520];
    for (int i = threadIdx.x; i < 512 * 16; i += 256)
        Wt[i & 15][i >> 4] = W[i];
    __syncthreads();
    const int wave = threadIdx.x >> 6;
    const int lane = threadIdx.x & 63;
    for (int row = blockIdx.x * 4 + wave; row < nRows; row += gridDim.x * 4) {
        const float* r = rows + (size_t)row * 512;
        float acc[16];
        #pragma unroll
        for (int o = 0; o < 16; ++o) acc[o] = 0.f;
        #pragma unroll
        for (int p = 0; p < 2; ++p) {
            float4 v = *reinterpret_cast<const float4*>(r + p * 256 + lane * 4);
            #pragma unroll
            for (int o = 0; o < 16; ++o) {
                float4 w = *reinterpret_cast<const float4*>(&Wt[o][p * 256 + lane * 4]);
                acc[o] += v.x * w.x + v.y * w.y + v.z * w.z + v.w * w.w;
            }
        }
        #pragma unroll
        for (int s = 32; s > 0; s >>= 1) {
            #pragma unroll
            for (int o = 0; o < 16; ++o) acc[o] += __shfl_xor(acc[o], s);
        }
        float vout = acc[0];
        #pragma unroll
        for (int o = 1; o < 16; ++o) vout = (lane == o) ? acc[o] : vout;
        if (lane < 16) out[(size_t)row * 16 + lane] = vout;
    }
}

// ---------------------------------------------------------------------------
// fp32 GEMM: C[M x 512] = A[M x 512] @ B[512 x 512] (+ bias), row-major.
// 64x64 tile, BK=16, 256 threads, 4x4 register tile.
__global__ __launch_bounds__(256) void gemm_f32(
    const float* __restrict__ A, const float* __restrict__ B,
    float* __restrict__ C, int M, const float* __restrict__ bias)
{
    __shared__ __align__(16) float As[16][68];
    __shared__ __align__(16) float Bs[16][68];
    const int t = threadIdx.x;
    const int row0 = blockIdx.x * 64;
    const int col0 = blockIdx.y * 64;
    const int lr = t >> 2;
    const int lk = (t & 3) * 4;
    const int lbk = t >> 4;
    const int lbn = (t & 15) * 4;
    const int tm = (t >> 4) * 4;
    const int tn = (t & 15) * 4;
    float c[4][4] = {{0.f}};
    const int ar = row0 + lr;
    const bool aok = ar < M;
    for (int k0 = 0; k0 < 512; k0 += 16) {
        float4 a4 = aok ? *reinterpret_cast<const float4*>(A + (size_t)ar * 512 + k0 + lk)
                        : make_float4(0.f, 0.f, 0.f, 0.f);
        As[lk + 0][lr] = a4.x; As[lk + 1][lr] = a4.y;
        As[lk + 2][lr] = a4.z; As[lk + 3][lr] = a4.w;
        *reinterpret_cast<float4*>(&Bs[lbk][lbn]) =
            *reinterpret_cast<const float4*>(B + (size_t)(k0 + lbk) * 512 + col0 + lbn);
        __syncthreads();
        #pragma unroll
        for (int k = 0; k < 16; ++k) {
            float4 av = *reinterpret_cast<const float4*>(&As[k][tm]);
            float4 bv = *reinterpret_cast<const float4*>(&Bs[k][tn]);
            c[0][0] += av.x * bv.x; c[0][1] += av.x * bv.y; c[0][2] += av.x * bv.z; c[0][3] += av.x * bv.w;
            c[1][0] += av.y * bv.x; c[1][1] += av.y * bv.y; c[1][2] += av.y * bv.z; c[1][3] += av.y * bv.w;
            c[2][0] += av.z * bv.x; c[2][1] += av.z * bv.y; c[2][2] += av.z * bv.z; c[2][3] += av.z * bv.w;
            c[3][0] += av.w * bv.x; c[3][1] += av.w * bv.y; c[3][2] += av.w * bv.z; c[3][3] += av.w * bv.w;
        }
        __syncthreads();
    }
    float4 bb = make_float4(0.f, 0.f, 0.f, 0.f);
    if (bias) bb = *reinterpret_cast<const float4*>(bias + col0 + tn);
    #pragma unroll
    for (int i = 0; i < 4; ++i) {
        int r = row0 + tm + i;
        if (r < M) {
            float4 o;
            o.x = c[i][0] + bb.x; o.y = c[i][1] + bb.y;
            o.z = c[i][2] + bb.z; o.w = c[i][3] + bb.w;
            *reinterpret_cast<float4*>(C + (size_t)r * 512 + col0 + tn) = o;
        }
    }
}

// ---------------------------------------------------------------------------
// CSR build for the TD direction (3 level blocks of 80000 edges, 5000 targets each)
__global__ void csr_zero(int* cnt) {
    int i = blockIdx.x * 256 + threadIdx.x;
    if (i < 15000) cnt[i] = 0;
}
__global__ void csr_count(const int* __restrict__ ei, int* __restrict__ cnt) {
    int e = blockIdx.x * 256 + threadIdx.x;
    if (e >= NE) return;
    int lv = e / EPB;
    int local = ei[e] - lv * PER;   // orig src is the TD target; lives in level lv
    atomicAdd(&cnt[lv * PER + local], 1);
}
__global__ void csr_scan(const int* __restrict__ cnt, int* __restrict__ rptr) {
    __shared__ int part[256];
    int lv = blockIdx.x, t = threadIdx.x;
    int s = 0;
    if (t < 250)
        for (int j = 0; j < 20; ++j) s += cnt[lv * PER + t * 20 + j];
    part[t] = s;
    __syncthreads();
    if (t == 0) {
        int run = 0;
        for (int i = 0; i < 250; ++i) { int v = part[i]; part[i] = run; run += v; }
        rptr[lv * 5001 + 5000] = run;
    }
    __syncthreads();
    if (t < 250) {
        int run = part[t];
        for (int j = 0; j < 20; ++j) {
            int idx = t * 20 + j;
            rptr[lv * 5001 + idx] = run;
            run += cnt[lv * PER + idx];
        }
    }
}
__global__ void csr_offinit(const int* __restrict__ rptr, int* __restrict__ off) {
    int i = blockIdx.x * 256 + threadIdx.x;
    if (i >= 15000) return;
    int lv = i / PER, local = i - lv * PER;
    off[i] = rptr[lv * 5001 + local];
}
__global__ void csr_fill(const int* __restrict__ ei, int* __restrict__ off, int* __restrict__ eids) {
    int e = blockIdx.x * 256 + threadIdx.x;
    if (e >= NE) return;
    int lv = e / EPB;
    int local = ei[e] - lv * PER;
    int pos = atomicAdd(&off[lv * PER + local], 1);   // level-local position
    eids[lv * EPB + pos] = e;
}

// ---------------------------------------------------------------------------
// Attention + softmax + aggregation for one level. One block (512 thr) per target.
// xp/ajai are window-relative (window = [base, base+10000) global node rows).
template<bool FIXED>
__global__ __launch_bounds__(512) void attn_kernel(
    const float* __restrict__ xp,    // [10000][512]
    const float* __restrict__ ajai,  // [10000][16]  (0-7 aj, 8-15 ai)
    const float* __restrict__ epA,   // [NE][16]     (0-7 bu, 8-15 td)
    const int* __restrict__ srcArr,  // global edge -> src node id (this direction)
    const int* __restrict__ rptr,    // TD only (level-local)
    const int* __restrict__ eids,    // TD only (level-local -> global edge id)
    int eBase,                       // BU only: first edge of block
    int base,                        // window base (global node id)
    int tgtLocOff,                   // xp-local offset of targets (BU:5000, TD:0)
    int dirOff,                      // epA column offset (BU:0, TD:8)
    float* __restrict__ aggn)        // [5000][512]
{
    __shared__ float Lwe[MAXDEG][8];
    __shared__ int   Lsrci[MAXDEG];
    __shared__ float Lws[8];
    __shared__ float Ldenom[8];
    const int t = blockIdx.x;
    const int tid = threadIdx.x;
    const int tgtXp = tgtLocOff + t;

    int deg, ebase;
    if (FIXED) { deg = DEG; ebase = eBase + t * DEG; }
    else       { int r0 = rptr[t]; deg = rptr[t + 1] - r0; ebase = r0; }
    if (deg > MAXDEG) deg = MAXDEG;

    for (int kk = tid; kk < deg * 8; kk += 512) {
        int k = kk >> 3, h = kk & 7;
        int e = FIXED ? (ebase + k) : eids[ebase + k];
        int src = srcArr[e] - base;
        float lg = (ajai[src * 16 + h] + ajai[tgtXp * 16 + 8 + h] + epA[(size_t)e * 16 + dirOff + h]) * SCALE;
        Lwe[k][h] = lg;
        if (h == 0) Lsrci[k] = src;
    }
    if (tid < 8) Lws[tid] = (ajai[tgtXp * 16 + tid] + ajai[tgtXp * 16 + 8 + tid]) * SCALE;
    __syncthreads();
    if (tid < 8) {
        float m = Lws[tid];
        for (int k = 0; k < deg; ++k) m = fmaxf(m, Lwe[k][tid]);
        float dsum = 0.f;
        for (int k = 0; k < deg; ++k) {
            float w = expf(Lwe[k][tid] - m);
            Lwe[k][tid] = w;
            dsum += w;
        }
        float wsv = expf(Lws[tid] - m);
        Lws[tid] = wsv;
        Ldenom[tid] = dsum + wsv;
    }
    __syncthreads();
    const int h = tid >> 6, c = tid & 63;
    float acc = Lws[h] * xp[(size_t)tgtXp * 512 + h * 64 + c];
    for (int k = 0; k < deg; ++k)
        acc += Lwe[k][h] * xp[(size_t)Lsrci[k] * 512 + h * 64 + c];
    aggn[(size_t)t * 512 + h * 64 + c] = acc / Ldenom[h];
}

// ---------------------------------------------------------------------------
extern "C" void kernel_launch(void* const* d_in, const int* in_sizes, int n_in,
                              void* d_out, int out_size, void* d_ws, size_t ws_size,
                              hipStream_t stream) {
    const float* node_feats = (const float*)d_in[0];
    const float* edge_feats = (const float*)d_in[1];
    const int*   edge_index = (const int*)d_in[2];
    const float* Wn_bu  = (const float*)d_in[5];
    const float* We_bu  = (const float*)d_in[6];
    const float* attn_bu = (const float*)d_in[7];
    const float* Wo_bu  = (const float*)d_in[8];
    const float* bo_bu  = (const float*)d_in[9];
    const float* Wn_td  = (const float*)d_in[10];
    const float* We_td  = (const float*)d_in[11];
    const float* attn_td = (const float*)d_in[12];
    const float* Wo_td  = (const float*)d_in[13];
    const float* bo_td  = (const float*)d_in[14];

    float* out = (float*)d_out;
    float* td = out;
    float* bu = out + (size_t)NV * DD;

    float* ws   = (float*)d_ws;
    float* xp   = ws;                         // 10000*512    = 5,120,000
    float* aggn = xp + 5120000;               // 5000*512     = 2,560,000
    float* ajai = aggn + 2560000;             // 10000*16     = 160,000
    float* epA  = ajai + 160000;              // 240000*16    = 3,840,000
    float* fold = epA + 3840000;              // 3*8192       = 24,576
    int* cnt  = (int*)(fold + 24576);         // 15,000
    int* off  = cnt + 15000;                  // 15,000
    int* rptr = off + 15000;                  // 3*5001 -> pad 15,008
    int* eids = rptr + 15008;                 // 240,000

    const int* ei_src = edge_index;           // orig src
    const int* ei_tgt = edge_index + NE;      // orig tgt

    init_copy<<<10000, 256, 0, stream>>>(node_feats, out);
    fold_kernel<<<96, 256, 0, stream>>>(Wn_bu, attn_bu, Wn_td, attn_td, We_bu, We_td, fold);
    rowdot16<<<4096, 256, 0, stream>>>(edge_feats, NE, fold + 16384, epA);

    csr_zero<<<59, 256, 0, stream>>>(cnt);
    csr_count<<<938, 256, 0, stream>>>(ei_src, cnt);
    csr_scan<<<3, 256, 0, stream>>>(cnt, rptr);
    csr_offinit<<<59, 256, 0, stream>>>(rptr, off);
    csr_fill<<<938, 256, 0, stream>>>(ei_src, off, eids);

    // Bottom-up: level l updates nodes [l*PER,(l+1)*PER) from level l-1
    for (int l = 1; l <= 3; ++l) {
        int base = (l - 1) * PER;
        gemm_f32<<<dim3(157, 8), 256, 0, stream>>>(bu + (size_t)base * DD, Wn_bu, xp, 10000, nullptr);
        rowdot16<<<2500, 256, 0, stream>>>(bu + (size_t)base * DD, 10000, fold, ajai);
        attn_kernel<true><<<5000, 512, 0, stream>>>(xp, ajai, epA, ei_src,
                                                    nullptr, nullptr, (l - 1) * EPB,
                                                    base, PER, 0, aggn);
        gemm_f32<<<dim3(79, 8), 256, 0, stream>>>(aggn, Wo_bu, bu + (size_t)(l * PER) * DD, 5000, bo_bu);
    }
    // Top-down: iter ltd updates orig level (3-ltd) from orig level (4-ltd), via reversed block 4-ltd
    for (int ltd = 1; ltd <= 3; ++ltd) {
        int lvIdx = 3 - ltd;                 // = lb-1, the CSR block index
        int base = lvIdx * PER;
        gemm_f32<<<dim3(157, 8), 256, 0, stream>>>(td + (size_t)base * DD, Wn_td, xp, 10000, nullptr);
        rowdot16<<<2500, 256, 0, stream>>>(td + (size_t)base * DD, 10000, fold + 8192, ajai);
        attn_kernel<false><<<5000, 512, 0, stream>>>(xp, ajai, epA, ei_tgt,
                                                     rptr + lvIdx * 5001, eids + lvIdx * EPB, 0,
                                                     base, 0, 8, aggn);
        gemm_f32<<<dim3(79, 8), 256, 0, stream>>>(aggn, Wo_td, td + (size_t)base * DD, 5000, bo_td);
    }
}

// Round 2
// 1247.483 us; speedup vs baseline: 1.5720x; 1.5720x over previous
//
#include <hip/hip_runtime.h>

// Problem constants (fixed-shape problem)
#define NV 20000
#define NE 240000
#define PER 5000
#define DEG 16
#define EPB 80000            // edges per level block
#define SCALE 0.07216878364870323f   // (3*64)^-0.5
#define MAXDEG 96

typedef __attribute__((ext_vector_type(8))) short s16x8;   // 8 bf16 in 4 VGPRs
typedef __attribute__((ext_vector_type(4))) float f32x4;   // MFMA accumulator

__device__ inline ushort bf16rne(float x) {
    uint32_t u = __float_as_uint(x);
    u += 0x7fffu + ((u >> 16) & 1u);
    return (ushort)(u >> 16);
}
__device__ inline s16x8 cvt8(float4 a, float4 b) {
    s16x8 v;
    v[0] = (short)bf16rne(a.x); v[1] = (short)bf16rne(a.y);
    v[2] = (short)bf16rne(a.z); v[3] = (short)bf16rne(a.w);
    v[4] = (short)bf16rne(b.x); v[5] = (short)bf16rne(b.y);
    v[6] = (short)bf16rne(b.z); v[7] = (short)bf16rne(b.w);
    return v;
}

// ---------------------------------------------------------------------------
// init: copy node_feats into both output halves (td at 0, bu at NV*512)
__global__ void init_copy(const float* __restrict__ nf, float* __restrict__ out) {
    int i = blockIdx.x * 256 + threadIdx.x;              // exactly NV*512/4 threads
    float4 v = reinterpret_cast<const float4*>(nf)[i];
    reinterpret_cast<float4*>(out)[i] = v;
    reinterpret_cast<float4*>(out + (size_t)NV * 512)[i] = v;
}

// ---------------------------------------------------------------------------
// fold: build 3 bf16 [16][512] matrices (transposed fold, MFMA-B-ready):
//  arr0 = Wn_bu fold (rows 0-7 aw_j, 8-15 aw_i)
//  arr1 = Wn_td fold
//  arr2 = We fold (rows 0-7 bu edge-alpha, 8-15 td)
__global__ void fold_kernel(
    const float* __restrict__ Wn_bu, const float* __restrict__ attn_bu,
    const float* __restrict__ Wn_td, const float* __restrict__ attn_td,
    const float* __restrict__ We_bu, const float* __restrict__ We_td,
    ushort* __restrict__ foldT)
{
    int idx = blockIdx.x * 256 + threadIdx.x;
    if (idx >= 3 * 8192) return;
    int arr = idx >> 13;
    int r = idx & 8191;
    int d = r >> 4;
    int o = r & 15;
    int h = o & 7;
    const float* W; const float* attn; int awOff;
    if (arr == 0)      { W = Wn_bu; attn = attn_bu; awOff = (o < 8) ? 0 : 64; }
    else if (arr == 1) { W = Wn_td; attn = attn_td; awOff = (o < 8) ? 0 : 64; }
    else               { W = (o < 8) ? We_bu : We_td; attn = (o < 8) ? attn_bu : attn_td; awOff = 128; }
    float s = 0.f;
    for (int cc = 0; cc < 64; ++cc)
        s += W[d * 512 + h * 64 + cc] * attn[h * 192 + awOff + cc];
    foldT[arr * 8192 + o * 512 + d] = bf16rne(s);
}

// ---------------------------------------------------------------------------
// prep_w: transpose+convert 4 [512][512] fp32 weights to bf16 Bt[n][k].
// 256 blocks (4 mats x 8x8 tiles of 64x64), 256 threads.
__global__ __launch_bounds__(256) void prep_w(
    const float* __restrict__ W0, const float* __restrict__ W1,
    const float* __restrict__ W2, const float* __restrict__ W3,
    ushort* __restrict__ Bt)
{
    __shared__ float T[64][65];
    const int t = threadIdx.x;
    const int b = blockIdx.x;
    const int mat = b >> 6;
    const int tk = (b >> 3) & 7, tn = b & 7;
    const float* W = (mat == 0) ? W0 : (mat == 1) ? W1 : (mat == 2) ? W2 : W3;
    const int k0 = tk * 64, n0 = tn * 64;
    #pragma unroll
    for (int i = 0; i < 4; ++i) {
        int r = (t >> 4) * 4 + i;
        int c = (t & 15) * 4;
        float4 v = *reinterpret_cast<const float4*>(W + (size_t)(k0 + r) * 512 + n0 + c);
        T[r][c + 0] = v.x; T[r][c + 1] = v.y; T[r][c + 2] = v.z; T[r][c + 3] = v.w;
    }
    __syncthreads();
    #pragma unroll
    for (int i = 0; i < 4; ++i) {
        int n = (t >> 4) * 4 + i;
        int c = (t & 15) * 4;
        ushort4 o;
        o.x = bf16rne(T[c + 0][n]); o.y = bf16rne(T[c + 1][n]);
        o.z = bf16rne(T[c + 2][n]); o.w = bf16rne(T[c + 3][n]);
        *reinterpret_cast<ushort4*>(Bt + (size_t)mat * 262144 + (size_t)(n0 + n) * 512 + k0 + c) = o;
    }
}

// ---------------------------------------------------------------------------
// rowdot_mfma: out[r][0..16) = rows[r][0..512) @ BtT[o][...]  via MFMA N=16.
// One wave per 16-row tile; A loaded straight from global in fragment layout;
// Bt (bf16 [16][512]) staged once into LDS (padded row 520 -> conflict-free).
__global__ __launch_bounds__(256) void rowdot_mfma(
    const float* __restrict__ A, int nTiles,
    const ushort* __restrict__ Bt16, float* __restrict__ out)
{
    __shared__ ushort Bs[16][520];
    const int t = threadIdx.x;
    for (int i = t; i < 16 * 512; i += 256)
        Bs[i >> 9][i & 511] = Bt16[i];
    __syncthreads();
    const int wave = t >> 6, lane = t & 63;
    const int tile = blockIdx.x * 4 + wave;
    if (tile >= nTiles) return;
    const int fr = lane & 15;            // A row / B col
    const int fk = (lane >> 4) * 8;      // k-group base
    const float* Ar = A + (size_t)tile * 16 * 512 + (size_t)fr * 512;
    f32x4 acc = {0.f, 0.f, 0.f, 0.f};
    #pragma unroll
    for (int k0 = 0; k0 < 512; k0 += 32) {
        float4 a0 = *reinterpret_cast<const float4*>(Ar + k0 + fk);
        float4 a1 = *reinterpret_cast<const float4*>(Ar + k0 + fk + 4);
        s16x8 av = cvt8(a0, a1);
        s16x8 bv = *reinterpret_cast<const s16x8*>(&Bs[fr][k0 + fk]);
        acc = __builtin_amdgcn_mfma_f32_16x16x32_bf16(av, bv, acc, 0, 0, 0);
    }
    #pragma unroll
    for (int i = 0; i < 4; ++i) {
        int r = tile * 16 + (lane >> 4) * 4 + i;
        out[(size_t)r * 16 + (lane & 15)] = acc[i];
    }
}

// ---------------------------------------------------------------------------
// gemm_mfma: C[M x 512] = A[M x 512 fp32] @ (Bt bf16, pre-transposed [n][k]) + bias
// 64x64 tile, 256 threads = 4 waves in 2x2, each wave 32x32 via 4 MFMAs/K-step.
__global__ __launch_bounds__(256) void gemm_mfma(
    const float* __restrict__ A, const ushort* __restrict__ Bt,
    float* __restrict__ C, int M, const float* __restrict__ bias)
{
    __shared__ ushort As[64][40];
    __shared__ ushort Bs[64][40];
    const int t = threadIdx.x;
    const int wave = t >> 6, lane = t & 63;
    const int row0 = blockIdx.x * 64, col0 = blockIdx.y * 64;
    const int wm = (wave >> 1) * 32, wn = (wave & 1) * 32;
    const int sm = t >> 2;              // staging row 0..63
    const int sk = (t & 3) * 8;         // staging k-offset
    const int fr = lane & 15;
    const int fk = (lane >> 4) * 8;
    const bool aok = (row0 + sm) < M;
    const float* Ap = A + (size_t)(row0 + sm) * 512;
    const ushort* Bp = Bt + (size_t)(col0 + sm) * 512;
    f32x4 acc[2][2];
    #pragma unroll
    for (int mi = 0; mi < 2; ++mi)
        #pragma unroll
        for (int ni = 0; ni < 2; ++ni) acc[mi][ni] = (f32x4){0.f, 0.f, 0.f, 0.f};

    for (int k0 = 0; k0 < 512; k0 += 32) {
        float4 a0, a1;
        if (aok) {
            a0 = *reinterpret_cast<const float4*>(Ap + k0 + sk);
            a1 = *reinterpret_cast<const float4*>(Ap + k0 + sk + 4);
        } else {
            a0 = make_float4(0.f, 0.f, 0.f, 0.f);
            a1 = a0;
        }
        *reinterpret_cast<s16x8*>(&As[sm][sk]) = cvt8(a0, a1);
        *reinterpret_cast<s16x8*>(&Bs[sm][sk]) =
            *reinterpret_cast<const s16x8*>(Bp + k0 + sk);
        __syncthreads();
        s16x8 af[2], bf[2];
        af[0] = *reinterpret_cast<const s16x8*>(&As[wm + fr][fk]);
        af[1] = *reinterpret_cast<const s16x8*>(&As[wm + 16 + fr][fk]);
        bf[0] = *reinterpret_cast<const s16x8*>(&Bs[wn + fr][fk]);
        bf[1] = *reinterpret_cast<const s16x8*>(&Bs[wn + 16 + fr][fk]);
        acc[0][0] = __builtin_amdgcn_mfma_f32_16x16x32_bf16(af[0], bf[0], acc[0][0], 0, 0, 0);
        acc[0][1] = __builtin_amdgcn_mfma_f32_16x16x32_bf16(af[0], bf[1], acc[0][1], 0, 0, 0);
        acc[1][0] = __builtin_amdgcn_mfma_f32_16x16x32_bf16(af[1], bf[0], acc[1][0], 0, 0, 0);
        acc[1][1] = __builtin_amdgcn_mfma_f32_16x16x32_bf16(af[1], bf[1], acc[1][1], 0, 0, 0);
        __syncthreads();
    }
    #pragma unroll
    for (int mi = 0; mi < 2; ++mi) {
        #pragma unroll
        for (int ni = 0; ni < 2; ++ni) {
            int c = col0 + wn + ni * 16 + (lane & 15);
            float bb = bias ? bias[c] : 0.f;
            #pragma unroll
            for (int i = 0; i < 4; ++i) {
                int r = row0 + wm + mi * 16 + (lane >> 4) * 4 + i;
                if (r < M) C[(size_t)r * 512 + c] = acc[mi][ni][i] + bb;
            }
        }
    }
}

// ---------------------------------------------------------------------------
// CSR build for the TD direction (3 level blocks of 80000 edges, 5000 targets each)
__global__ void csr_zero(int* cnt) {
    int i = blockIdx.x * 256 + threadIdx.x;
    if (i < 15000) cnt[i] = 0;
}
__global__ void csr_count(const int* __restrict__ ei, int* __restrict__ cnt) {
    int e = blockIdx.x * 256 + threadIdx.x;
    if (e >= NE) return;
    int lv = e / EPB;
    int local = ei[e] - lv * PER;   // orig src is the TD target; lives in level lv
    atomicAdd(&cnt[lv * PER + local], 1);
}
__global__ void csr_scan(const int* __restrict__ cnt, int* __restrict__ rptr) {
    __shared__ int part[256];
    int lv = blockIdx.x, t = threadIdx.x;
    int s = 0;
    if (t < 250)
        for (int j = 0; j < 20; ++j) s += cnt[lv * PER + t * 20 + j];
    part[t] = s;
    __syncthreads();
    if (t == 0) {
        int run = 0;
        for (int i = 0; i < 250; ++i) { int v = part[i]; part[i] = run; run += v; }
        rptr[lv * 5001 + 5000] = run;
    }
    __syncthreads();
    if (t < 250) {
        int run = part[t];
        for (int j = 0; j < 20; ++j) {
            int idx = t * 20 + j;
            rptr[lv * 5001 + idx] = run;
            run += cnt[lv * PER + idx];
        }
    }
}
__global__ void csr_offinit(const int* __restrict__ rptr, int* __restrict__ off) {
    int i = blockIdx.x * 256 + threadIdx.x;
    if (i >= 15000) return;
    int lv = i / PER, local = i - lv * PER;
    off[i] = rptr[lv * 5001 + local];
}
__global__ void csr_fill(const int* __restrict__ ei, int* __restrict__ off, int* __restrict__ eids) {
    int e = blockIdx.x * 256 + threadIdx.x;
    if (e >= NE) return;
    int lv = e / EPB;
    int local = ei[e] - lv * PER;
    int pos = atomicAdd(&off[lv * PER + local], 1);   // level-local position
    eids[lv * EPB + pos] = e;
}

// ---------------------------------------------------------------------------
// Attention + softmax + aggregation for one level. One block (512 thr) per target.
// xp/ajai are window-relative (window = [base, base+10000) global node rows).
template<bool FIXED>
__global__ __launch_bounds__(512) void attn_kernel(
    const float* __restrict__ xp,    // [10000][512]
    const float* __restrict__ ajai,  // [10000][16]  (0-7 aj, 8-15 ai)
    const float* __restrict__ epA,   // [NE][16]     (0-7 bu, 8-15 td)
    const int* __restrict__ srcArr,  // global edge -> src node id (this direction)
    const int* __restrict__ rptr,    // TD only (level-local)
    const int* __restrict__ eids,    // TD only (level-local -> global edge id)
    int eBase,                       // BU only: first edge of block
    int base,                        // window base (global node id)
    int tgtLocOff,                   // xp-local offset of targets (BU:5000, TD:0)
    int dirOff,                      // epA column offset (BU:0, TD:8)
    float* __restrict__ aggn)        // [5000][512]
{
    __shared__ float Lwe[MAXDEG][8];
    __shared__ int   Lsrci[MAXDEG];
    __shared__ float Lws[8];
    __shared__ float Ldenom[8];
    const int t = blockIdx.x;
    const int tid = threadIdx.x;
    const int tgtXp = tgtLocOff + t;

    int deg, ebase;
    if (FIXED) { deg = DEG; ebase = eBase + t * DEG; }
    else       { int r0 = rptr[t]; deg = rptr[t + 1] - r0; ebase = r0; }
    if (deg > MAXDEG) deg = MAXDEG;

    for (int kk = tid; kk < deg * 8; kk += 512) {
        int k = kk >> 3, h = kk & 7;
        int e = FIXED ? (ebase + k) : eids[ebase + k];
        int src = srcArr[e] - base;
        float lg = (ajai[src * 16 + h] + ajai[tgtXp * 16 + 8 + h] + epA[(size_t)e * 16 + dirOff + h]) * SCALE;
        Lwe[k][h] = lg;
        if (h == 0) Lsrci[k] = src;
    }
    if (tid < 8) Lws[tid] = (ajai[tgtXp * 16 + tid] + ajai[tgtXp * 16 + 8 + tid]) * SCALE;
    __syncthreads();
    if (tid < 8) {
        float m = Lws[tid];
        for (int k = 0; k < deg; ++k) m = fmaxf(m, Lwe[k][tid]);
        float dsum = 0.f;
        for (int k = 0; k < deg; ++k) {
            float w = expf(Lwe[k][tid] - m);
            Lwe[k][tid] = w;
            dsum += w;
        }
        float wsv = expf(Lws[tid] - m);
        Lws[tid] = wsv;
        Ldenom[tid] = dsum + wsv;
    }
    __syncthreads();
    const int h = tid >> 6, c = tid & 63;
    float acc = Lws[h] * xp[(size_t)tgtXp * 512 + h * 64 + c];
    if (FIXED) {
        #pragma unroll
        for (int k = 0; k < DEG; ++k)
            acc += Lwe[k][h] * xp[(size_t)Lsrci[k] * 512 + h * 64 + c];
    } else {
        #pragma unroll 4
        for (int k = 0; k < deg; ++k)
            acc += Lwe[k][h] * xp[(size_t)Lsrci[k] * 512 + h * 64 + c];
    }
    aggn[(size_t)t * 512 + h * 64 + c] = acc / Ldenom[h];
}

// ---------------------------------------------------------------------------
extern "C" void kernel_launch(void* const* d_in, const int* in_sizes, int n_in,
                              void* d_out, int out_size, void* d_ws, size_t ws_size,
                              hipStream_t stream) {
    const float* node_feats = (const float*)d_in[0];
    const float* edge_feats = (const float*)d_in[1];
    const int*   edge_index = (const int*)d_in[2];
    const float* Wn_bu  = (const float*)d_in[5];
    const float* We_bu  = (const float*)d_in[6];
    const float* attn_bu = (const float*)d_in[7];
    const float* Wo_bu  = (const float*)d_in[8];
    const float* bo_bu  = (const float*)d_in[9];
    const float* Wn_td  = (const float*)d_in[10];
    const float* We_td  = (const float*)d_in[11];
    const float* attn_td = (const float*)d_in[12];
    const float* Wo_td  = (const float*)d_in[13];
    const float* bo_td  = (const float*)d_in[14];

    float* out = (float*)d_out;
    float* td = out;
    float* bu = out + (size_t)NV * 512;

    float* ws   = (float*)d_ws;
    float* xp   = ws;                         // 10000*512    = 5,120,000
    float* aggn = xp + 5120000;               // 5000*512     = 2,560,000
    float* ajai = aggn + 2560000;             // 10000*16     = 160,000
    float* epA  = ajai + 160000;              // 240000*16    = 3,840,000
    int* cnt  = (int*)(epA + 3840000);        // 15,000
    int* off  = cnt + 15000;                  // 15,000
    int* rptr = off + 15000;                  // 3*5001 -> pad 15,008
    int* eids = rptr + 15008;                 // 240,000
    ushort* BtW   = (ushort*)(eids + 240000); // 4*262144 bf16 (Wn_bu,Wo_bu,Wn_td,Wo_td transposed)
    ushort* foldT = BtW + 4 * 262144;         // 3*8192 bf16

    const int* ei_src = edge_index;           // orig src
    const int* ei_tgt = edge_index + NE;      // orig tgt

    init_copy<<<10000, 256, 0, stream>>>(node_feats, out);
    fold_kernel<<<96, 256, 0, stream>>>(Wn_bu, attn_bu, Wn_td, attn_td, We_bu, We_td, foldT);
    prep_w<<<256, 256, 0, stream>>>(Wn_bu, Wo_bu, Wn_td, Wo_td, BtW);
    rowdot_mfma<<<3750, 256, 0, stream>>>(edge_feats, 15000, foldT + 2 * 8192, epA);

    csr_zero<<<59, 256, 0, stream>>>(cnt);
    csr_count<<<938, 256, 0, stream>>>(ei_src, cnt);
    csr_scan<<<3, 256, 0, stream>>>(cnt, rptr);
    csr_offinit<<<59, 256, 0, stream>>>(rptr, off);
    csr_fill<<<938, 256, 0, stream>>>(ei_src, off, eids);

    // Bottom-up: level l updates nodes [l*PER,(l+1)*PER) from level l-1
    for (int l = 1; l <= 3; ++l) {
        int base = (l - 1) * PER;
        gemm_mfma<<<dim3(157, 8), 256, 0, stream>>>(bu + (size_t)base * 512, BtW, xp, 10000, nullptr);
        rowdot_mfma<<<157, 256, 0, stream>>>(bu + (size_t)base * 512, 625, foldT, ajai);
        attn_kernel<true><<<5000, 512, 0, stream>>>(xp, ajai, epA, ei_src,
                                                    nullptr, nullptr, (l - 1) * EPB,
                                                    base, PER, 0, aggn);
        gemm_mfma<<<dim3(79, 8), 256, 0, stream>>>(aggn, BtW + 262144, bu + (size_t)(l * PER) * 512, 5000, bo_bu);
    }
    // Top-down: iter ltd updates orig level (3-ltd) from orig level (4-ltd), via reversed block 4-ltd
    for (int ltd = 1; ltd <= 3; ++ltd) {
        int lvIdx = 3 - ltd;                 // CSR block index
        int base = lvIdx * PER;
        gemm_mfma<<<dim3(157, 8), 256, 0, stream>>>(td + (size_t)base * 512, BtW + 2 * 262144, xp, 10000, nullptr);
        rowdot_mfma<<<157, 256, 0, stream>>>(td + (size_t)base * 512, 625, foldT + 8192, ajai);
        attn_kernel<false><<<5000, 512, 0, stream>>>(xp, ajai, epA, ei_tgt,
                                                     rptr + lvIdx * 5001, eids + lvIdx * EPB, 0,
                                                     base, 0, 8, aggn);
        gemm_mfma<<<dim3(79, 8), 256, 0, stream>>>(aggn, BtW + 3 * 262144, td + (size_t)base * 512, 5000, bo_td);
    }
}